// Round 7
// baseline (898.098 us; speedup 1.0000x reference)
//
#include <hip/hip_runtime.h>
#include <hip/hip_bf16.h>

typedef unsigned short u16;
typedef unsigned int u32;
typedef __attribute__((ext_vector_type(8))) __bf16 bf16x8;
typedef __attribute__((ext_vector_type(8))) unsigned short u16x8;
typedef __attribute__((ext_vector_type(4))) float floatx4;
typedef __attribute__((ext_vector_type(16))) float floatx16;

#define AS1 __attribute__((address_space(1)))
#define AS3 __attribute__((address_space(3)))

__device__ __forceinline__ u16 f2bf(float f) {
  unsigned u = __float_as_uint(f);
  u += 0x7fffu + ((u >> 16) & 1u);   // round-to-nearest-even (inputs finite)
  return (u16)(u >> 16);
}

__device__ __forceinline__ void g2lds16(const u16* g, u16* l) {
  __builtin_amdgcn_global_load_lds((AS1 void*)g, (AS3 void*)l, 16, 0, 0);
}

// ---------------- fp32 -> bf16 convert (vectorized) ----------------
__global__ __launch_bounds__(256) void k_cvt_bf16(const float* __restrict__ s,
                                                  u16* __restrict__ d, long n) {
  long i = ((long)blockIdx.x * blockDim.x + threadIdx.x) * 8;
  long stride = (long)gridDim.x * blockDim.x * 8;
  for (; i < n; i += stride) {
    float4 a = *(const float4*)(s + i);
    float4 b = *(const float4*)(s + i + 4);
    u16x8 o;
    o[0] = f2bf(a.x); o[1] = f2bf(a.y); o[2] = f2bf(a.z); o[3] = f2bf(a.w);
    o[4] = f2bf(b.x); o[5] = f2bf(b.y); o[6] = f2bf(b.z); o[7] = f2bf(b.w);
    *(u16x8*)(d + i) = o;
  }
}

// ---------------- (Wk + Wv) -> bf16 ----------------
__global__ __launch_bounds__(256) void k_addcvt(const float* __restrict__ s0,
                                                const float* __restrict__ s1,
                                                u16* __restrict__ d, long n) {
  long i = ((long)blockIdx.x * blockDim.x + threadIdx.x) * 8;
  long stride = (long)gridDim.x * blockDim.x * 8;
  for (; i < n; i += stride) {
    float4 a0 = *(const float4*)(s0 + i);
    float4 a1 = *(const float4*)(s0 + i + 4);
    float4 b0 = *(const float4*)(s1 + i);
    float4 b1 = *(const float4*)(s1 + i + 4);
    u16x8 o;
    o[0] = f2bf(a0.x + b0.x); o[1] = f2bf(a0.y + b0.y);
    o[2] = f2bf(a0.z + b0.z); o[3] = f2bf(a0.w + b0.w);
    o[4] = f2bf(a1.x + b1.x); o[5] = f2bf(a1.y + b1.y);
    o[6] = f2bf(a1.z + b1.z); o[7] = f2bf(a1.w + b1.w);
    *(u16x8*)(d + i) = o;
  }
}

// ---------------- transpose + convert: src fp32 [R][C] -> dst bf16 [C][R] ----------------
__global__ __launch_bounds__(256) void k_tcvt(const float* __restrict__ s,
                                              u16* __restrict__ d, int R, int C) {
  __shared__ float t[32][33];
  const int lx = threadIdx.x, ly = threadIdx.y;
  const int bx = blockIdx.x * 32;  // col of src
  const int by = blockIdx.y * 32;  // row of src
  #pragma unroll
  for (int i = 0; i < 32; i += 8)
    t[ly + i][lx] = s[(size_t)(by + ly + i) * C + bx + lx];
  __syncthreads();
  #pragma unroll
  for (int i = 0; i < 32; i += 8)
    d[(size_t)(bx + ly + i) * R + by + lx] = f2bf(t[lx][ly + i]);
}

// ============ 128x128 4-wave bf16 GEMM (round-4 proven: 16x16x32 + T2 + T1) ============
#define MFMA16(a, b, c) c = __builtin_amdgcn_mfma_f32_16x16x32_bf16(a, b, c, 0, 0, 0)
#define MFMA32(a, b, c) c = __builtin_amdgcn_mfma_f32_32x32x16_bf16(a, b, c, 0, 0, 0)

template <int MODE>
__global__ __launch_bounds__(256, 3) void gemm128(
    const u16* __restrict__ A, const u16* __restrict__ Bt,
    int M, int N, int K, int ntn,
    u16* __restrict__ Cb, float* __restrict__ Cf,
    const float* __restrict__ memp, float* __restrict__ latf, u16* __restrict__ latb) {
  __shared__ u16 As[128 * 64];
  __shared__ u16 Bs[128 * 64];
  const int tid = threadIdx.x;
  const int lane = tid & 63;
  const int wid = tid >> 6;          // 4 waves: 2x2
  const int wr = wid >> 1, wc = wid & 1;

  // bijective XCD-aware swizzle (m204)
  int bid = blockIdx.x;
  {
    const int nwg = gridDim.x;
    const int q = nwg >> 3, r = nwg & 7;
    const int xcd = bid & 7, idx = bid >> 3;
    bid = (xcd < r ? xcd * (q + 1) : r * (q + 1) + (xcd - r) * q) + idx;
  }
  const int mt = bid / ntn, nt = bid % ntn;
  const int m0 = mt * 128, n0 = nt * 128;

  const int fr = lane & 15;
  const int g8 = (lane >> 4) * 8;
  const int xr = (lane & 7) * 8;     // read-side XOR (u16 units); row&7 == lane&7

  floatx4 acc[4][4];
  #pragma unroll
  for (int i = 0; i < 4; i++)
    #pragma unroll
    for (int j = 0; j < 4; j++) acc[i][j] = 0.0f;

  const u16* Ag0 = A + (size_t)m0 * K;
  const u16* Bg0 = Bt + (size_t)n0 * K;

  for (int kt = 0; kt < K; kt += 64) {
    #pragma unroll
    for (int p = 0; p < 4; p++) {
      int ci = p * 256 + tid;
      int row = ci >> 3;
      int kc = ((ci & 7) ^ (row & 7)) * 8;   // pre-swizzled source col
      g2lds16(Ag0 + (size_t)row * K + kt + kc, &As[ci * 8]);
    }
    #pragma unroll
    for (int p = 0; p < 4; p++) {
      int ci = p * 256 + tid;
      int row = ci >> 3;
      int kc = ((ci & 7) ^ (row & 7)) * 8;
      g2lds16(Bg0 + (size_t)row * K + kt + kc, &Bs[ci * 8]);
    }
    __syncthreads();
    #pragma unroll
    for (int kk = 0; kk < 64; kk += 32) {
      const int koff = kk + g8;
      bf16x8 af[4], bfv[4];
      #pragma unroll
      for (int i = 0; i < 4; i++)
        af[i] = *(const bf16x8*)&As[(wr * 64 + i * 16 + fr) * 64 + (koff ^ xr)];
      #pragma unroll
      for (int j = 0; j < 4; j++)
        bfv[j] = *(const bf16x8*)&Bs[(wc * 64 + j * 16 + fr) * 64 + (koff ^ xr)];
      #pragma unroll
      for (int i = 0; i < 4; i++)
        #pragma unroll
        for (int j = 0; j < 4; j++)
          MFMA16(af[i], bfv[j], acc[i][j]);
    }
    __syncthreads();
  }

  #pragma unroll
  for (int i = 0; i < 4; i++) {
    const int mb = m0 + wr * 64 + i * 16 + ((lane >> 4) * 4);
    #pragma unroll
    for (int j = 0; j < 4; j++) {
      const int cb = n0 + wc * 64 + j * 16 + (lane & 15);
      #pragma unroll
      for (int r = 0; r < 4; r++) {
        const int m = mb + r;
        const float v = acc[i][j][r];
        if (MODE == 0) {
          Cb[(size_t)m * N + cb] = f2bf(v);
        } else if (MODE == 1) {
          if (n0 < 1024) {
            Cb[(size_t)m * 1024 + cb] = f2bf(v);   // q, ld=1024
          } else {
            int lc = cb - 1024;                     // latent col 0..255
            float lv = (v + memp[(size_t)m * 256 + lc]) * 0.5f;
            latf[(size_t)m * 256 + lc] = lv;        // fp32 output #2
            latb[(size_t)m * 256 + lc] = f2bf(lv);  // bf16 for attention
          }
        } else {
          Cf[(size_t)m * N + cb] = v;
        }
      }
    }
  }
}

// ============ fused absorbed attention (asm-free) ============
// Per block: one batch (32 tokens), 4 waves, wave w does heads {w, w+4, w+8, w+12}.
// Per head (all mfma_32x32x16; A: row=lane&31,k=(lane>>5)*8+j; B: col=lane&31,same k;
//           D: col=lane&31, row rr=(r&3)+8*(r>>2)+4*(lane>>5)):
//   1. q~^T[l,s]   = W_uk_h[l,d] x q_h[s,d]          32 MFMA
//   2. S^T[key,q]  = latent[key,l] x q~^T[l,q]       16 MFMA
//   3. softmax over keys in-register (lane=q holds 16 keys; partner lane^32 rest)
//   4. ctx~[l,q]   = latent^T[l,key] x P^T[key,q]    16 MFMA
//   5. ctx[q,d]    = ctx~^T[q,l] x W_uv[l,d]         32 MFMA
// D->operand repack via wave-private LDS tile T[32 cols][40] (no inline asm):
//   lane (c,hi) writes its 16 D-values as 8 u32 pairs at T[c][rr]; reads back
//   ds_read_b128 at T[c][hi*8] / T[c][16+hi*8] = A/B fragment layout.
__device__ __forceinline__ void pack_lds(u16* T, const floatx16& d,
                                         int col, int hi, bf16x8& f0, bf16x8& f1) {
  #pragma unroll
  for (int i = 0; i < 8; i++) {
    const int r = 2 * i;
    const int rr = (r & 3) + 8 * (r >> 2) + 4 * hi;      // even; rr+1 = odd partner
    const u32 wv = (u32)f2bf(d[r]) | ((u32)f2bf(d[r + 1]) << 16);
    *(u32*)&T[col * 40 + rr] = wv;
  }
  f0 = *(const bf16x8*)&T[col * 40 + hi * 8];            // rows 0..15 as k
  f1 = *(const bf16x8*)&T[col * 40 + 16 + hi * 8];       // rows 16..31 as k
}

__global__ __launch_bounds__(256, 3) void k_attn2(
    const u16* __restrict__ Lb,    // latent bf16 [65536][256]
    u16* __restrict__ Q,           // q bf16 [65536][1024]; ctx written in place
    const u16* __restrict__ Wuk,   // W_uk bf16 [256][1024]
    const u16* __restrict__ WuvT)  // W_uv^T bf16 [1024][256]
{
  __shared__ u16 Ls[32][264];      // latent rows
  __shared__ u16 LsT[256][40];     // latent transposed
  __shared__ u16 Tw[4][32][40];    // per-wave repack tile
  const int tid = threadIdx.x;
  const long tok0 = (long)blockIdx.x * 32;

  { // build Ls and LsT
    const int key = tid >> 3, c0 = (tid & 7) * 32;
    #pragma unroll
    for (int u = 0; u < 4; u++) {
      u16x8 v = *(const u16x8*)(Lb + (tok0 + key) * 256 + c0 + u * 8);
      *(u16x8*)&Ls[key][c0 + u * 8] = v;
      #pragma unroll
      for (int j = 0; j < 8; j++) LsT[c0 + u * 8 + j][key] = v[j];
    }
  }
  __syncthreads();

  const int w = tid >> 6;
  const int lane = tid & 63;
  const int col = lane & 31;
  const int hi = lane >> 5;
  const int hi8 = hi * 8;
  const int rhi4 = hi * 4;
  u16* T = &Tw[w][0][0];

  #pragma unroll 1
  for (int hh = 0; hh < 4; hh++) {
    const int h = w + hh * 4;

    // q B-frags: lane(col)=s holds q[tok0+s][h*64 + ks*16 + hi8 + j]
    const u16* qbase = Q + (tok0 + col) * 1024 + h * 64 + hi8;
    bf16x8 qf[4];
    #pragma unroll
    for (int ks = 0; ks < 4; ks++)
      qf[ks] = *(const bf16x8*)(qbase + ks * 16);

    // steps 1+2 fused per m-tile of l
    floatx16 St;
    #pragma unroll
    for (int r = 0; r < 16; r++) St[r] = 0.0f;
    #pragma unroll
    for (int mi = 0; mi < 8; mi++) {
      floatx16 qt;
      #pragma unroll
      for (int r = 0; r < 16; r++) qt[r] = 0.0f;
      #pragma unroll
      for (int ks = 0; ks < 4; ks++) {
        bf16x8 af = *(const bf16x8*)(Wuk + (size_t)(mi * 32 + col) * 1024 +
                                     h * 64 + ks * 16 + hi8);
        MFMA32(af, qf[ks], qt);
      }
      bf16x8 qg0, qg1;
      pack_lds(T, qt, col, hi, qg0, qg1);   // q~^T frags: l-subtiles [0..15],[16..31]
      bf16x8 la0 = *(const bf16x8*)&Ls[col][mi * 32 + hi8];
      MFMA32(la0, qg0, St);
      bf16x8 la1 = *(const bf16x8*)&Ls[col][mi * 32 + 16 + hi8];
      MFMA32(la1, qg1, St);
    }

    // step 3: softmax over keys; lane holds 16 keys (rr), partner lane^32 the rest
    float p[16];
    float mx = -3.4e38f;
    #pragma unroll
    for (int r = 0; r < 16; r++) { p[r] = St[r] * 0.03125f; mx = fmaxf(mx, p[r]); }
    mx = fmaxf(mx, __shfl_xor(mx, 32, 64));
    float sm = 0.0f;
    #pragma unroll
    for (int r = 0; r < 16; r++) { p[r] = __expf(p[r] - mx); sm += p[r]; }
    sm += __shfl_xor(sm, 32, 64);
    const float rs = 1.0f / sm;
    floatx16 Pt;
    #pragma unroll
    for (int r = 0; r < 16; r++) Pt[r] = p[r] * rs;
    bf16x8 pg0, pg1;
    pack_lds(T, Pt, col, hi, pg0, pg1);     // P^T frags: keys [0..15],[16..31]

    // steps 4+5 fused per m-tile of l
    floatx16 cacc0, cacc1;
    #pragma unroll
    for (int r = 0; r < 16; r++) { cacc0[r] = 0.0f; cacc1[r] = 0.0f; }
    const u16* wv0 = WuvT + (size_t)(h * 64 + col) * 256;
    const u16* wv1 = WuvT + (size_t)(h * 64 + 32 + col) * 256;
    #pragma unroll
    for (int mi = 0; mi < 8; mi++) {
      floatx16 ct;
      #pragma unroll
      for (int r = 0; r < 16; r++) ct[r] = 0.0f;
      bf16x8 lt0 = *(const bf16x8*)&LsT[mi * 32 + col][hi8];
      MFMA32(lt0, pg0, ct);
      bf16x8 lt1 = *(const bf16x8*)&LsT[mi * 32 + col][16 + hi8];
      MFMA32(lt1, pg1, ct);
      bf16x8 cg0, cg1;
      pack_lds(T, ct, col, hi, cg0, cg1);   // ctx~ A-frags: l-subtiles of this tile
      #pragma unroll
      for (int ksl = 0; ksl < 2; ksl++) {
        bf16x8 cg = ksl ? cg1 : cg0;
        bf16x8 b0 = *(const bf16x8*)(wv0 + mi * 32 + ksl * 16 + hi8);
        bf16x8 b1 = *(const bf16x8*)(wv1 + mi * 32 + ksl * 16 + hi8);
        MFMA32(cg, b0, cacc0);
        MFMA32(cg, b1, cacc1);
      }
    }

    // write ctx over q (this wave owns these columns)
    #pragma unroll
    for (int r = 0; r < 16; r++) {
      const int rr = (r & 3) + 8 * (r >> 2) + rhi4;
      u16* orow = Q + (tok0 + rr) * 1024 + h * 64;
      orow[col] = f2bf(cacc0[r]);
      orow[32 + col] = f2bf(cacc1[r]);
    }
  }
}

extern "C" void kernel_launch(void* const* d_in, const int* in_sizes, int n_in,
                              void* d_out, int out_size, void* d_ws, size_t ws_size,
                              hipStream_t stream) {
  const float* x    = (const float*)d_in[0];
  const float* mem  = (const float*)d_in[1];
  const float* W_q  = (const float*)d_in[2];
  const float* W_k  = (const float*)d_in[3];
  const float* W_v  = (const float*)d_in[4];
  const float* W_o  = (const float*)d_in[5];
  const float* W_dn = (const float*)d_in[6];
  const float* W_uk = (const float*)d_in[7];
  const float* W_uv = (const float*)d_in[8];
  float* out  = (float*)d_out;
  float* latf = out + (size_t)67108864;   // latent_kv fp32 output

  char* wp = (char*)d_ws;
  u16* Qb   = (u16*)wp; wp += (size_t)65536 * 1024 * 2;  // q / ctx bf16
  u16* Lb   = (u16*)wp; wp += (size_t)65536 * 256 * 2;   // latent bf16
  u16* WAt  = (u16*)wp; wp += (size_t)1280 * 1024 * 2;   // [W_q | W_kvd]^T
  u16* WuvT = (u16*)wp; wp += (size_t)1024 * 256 * 2;    // W_uv^T
  u16* Wot  = (u16*)wp; wp += (size_t)1024 * 1024 * 2;   // W_o^T
  u16* Wdt  = (u16*)wp; wp += (size_t)256 * 1024 * 2;    // W_down^T
  u16* Wkv  = (u16*)wp; wp += (size_t)1024 * 1024 * 2;   // (Wk+Wv) bf16
  u16* Wukb = (u16*)wp; wp += (size_t)256 * 1024 * 2;    // W_uk bf16 (row-major)

  u16* Xb = (u16*)d_out;  // x bf16 (aliased into out region; dead before GEMM3)

  dim3 b256(256);
  dim3 tb(32, 8);
  k_cvt_bf16<<<4096, b256, 0, stream>>>(x, Xb, (long)67108864);
  k_addcvt<<<512, b256, 0, stream>>>(W_k, W_v, Wkv, (long)1048576);
  k_cvt_bf16<<<128, b256, 0, stream>>>(W_uk, Wukb, (long)262144);
  k_tcvt<<<dim3(32, 32), tb, 0, stream>>>(W_q, WAt, 1024, 1024);
  k_tcvt<<<dim3(8, 32),  tb, 0, stream>>>(W_dn, Wdt, 1024, 256);
  k_tcvt<<<dim3(32, 8),  tb, 0, stream>>>(W_uv, WuvT, 256, 1024);
  k_tcvt<<<dim3(32, 32), tb, 0, stream>>>(W_o, Wot, 1024, 1024);

  // W_kvd^T = Wdt @ Wkv^T -> WAt rows 1024..1279  (M=256, N=1024)
  gemm128<0><<<16, b256, 0, stream>>>(
      Wdt, Wkv, 256, 1024, 1024, 8, WAt + (size_t)1024 * 1024,
      nullptr, nullptr, nullptr, nullptr);

  // GEMM1: [q | latent_pre] = x @ [W_q | W_kvd]   (512 x 10 tiles)
  gemm128<1><<<5120, b256, 0, stream>>>(
      Xb, WAt, 65536, 1280, 1024, 10, Qb, nullptr, mem, latf, Lb);

  // fused absorbed attention: q,latent -> ctx (in place over Qb)
  k_attn2<<<2048, b256, 0, stream>>>(Lb, Qb, Wukb, WuvT);

  // GEMM3: out = ctx @ W_o (fp32)   (512 x 8 tiles)
  gemm128<2><<<4096, b256, 0, stream>>>(
      Qb, Wot, 65536, 1024, 1024, 8, nullptr, out, nullptr, nullptr, nullptr);
}